// Round 3
// baseline (74.319 us; speedup 1.0000x reference)
//
#include <hip/hip_runtime.h>

// Problem constants (match reference)
constexpr int BS = 16, Q = 1000, NC = 80, T = 100, NI = 8;
constexpr int CTOT = BS * Q * T;        // 1,600,000 C_diag entries
constexpr int ITOT = BS * Q * NI;       //   128,000 ioa_diag entries
constexpr int NCT  = CTOT / 4;          // 400,000 threads, 4 C outputs each
constexpr int NIT  = ITOT / 4;          //  32,000 threads, 4 ioa outputs each
constexpr int NTHREADS = NCT + NIT;     // 432,000

#define ALPHA   0.25f
#define W_CLASS 2.0f
#define W_BBOX  5.0f
#define W_GIOU  2.0f

__device__ __forceinline__ float rcp(float x)  { return __builtin_amdgcn_rcpf(x); }
__device__ __forceinline__ float ex2(float x)  { return __builtin_amdgcn_exp2f(x); }
__device__ __forceinline__ float lg2(float x)  { return __builtin_amdgcn_logf(x); }
#define LOG2E 1.44269504088896f
#define LN2   0.69314718055995f

// 4 outputs per thread; float4 stores. Layout matches d_out exactly:
// C_diag (BS*Q*T) ++ ioa_diag (BS*Q*NI).
__global__ __launch_bounds__(256) void matcher_kernel(
    const float* __restrict__ pred_logits,   // (BS,Q,NC)
    const float* __restrict__ pred_boxes,    // (BS,Q,4)
    const float* __restrict__ tgt_bbox,      // (BS*T,4)
    const float* __restrict__ ign_bbox,      // (BS*NI,4)
    const float* __restrict__ img_sz,        // (BS,4)
    const float* __restrict__ img_sz_tgt,    // (BS*T,4)
    const int*   __restrict__ tgt_ids,       // (BS*T,)
    float* __restrict__ out)
{
    const int t = blockIdx.x * 256 + threadIdx.x;
    if (t >= NTHREADS) return;

    if (t < NCT) {
        const int n  = t / 25;           // 25 groups of 4 targets per query
        const int g  = t - n * 25;
        const int j0 = g * 4;
        const int b  = n / Q;
        const int r0 = b * T + j0;       // multiple of 4 -> 16B-aligned rows

        const float4 pb  = *(const float4*)(pred_boxes + (size_t)n * 4);
        const float4 isz = *(const float4*)(img_sz     + (size_t)b * 4);
        // Hoisted: shared across 4 outputs
        const float obx = pb.x * rcp(isz.x);
        const float oby = pb.y * rcp(isz.y);
        const float obz = pb.z * rcp(isz.z);
        const float obw = pb.w * rcp(isz.w);
        const float area_p = (pb.z - pb.x) * (pb.w - pb.y);
        const int4 cls4 = *(const int4*)(tgt_ids + r0);
        const int cls[4] = {cls4.x, cls4.y, cls4.z, cls4.w};

        float res[4];
        #pragma unroll
        for (int k = 0; k < 4; ++k) {
            const int r = r0 + k;
            const float4 tb  = *(const float4*)(tgt_bbox   + (size_t)r * 4);
            const float4 tsz = *(const float4*)(img_sz_tgt + (size_t)r * 4);

            // cost_bbox
            const float cb = fabsf(obx - tb.x * rcp(tsz.x))
                           + fabsf(oby - tb.y * rcp(tsz.y))
                           + fabsf(obz - tb.z * rcp(tsz.z))
                           + fabsf(obw - tb.w * rcp(tsz.w));

            // cost_class (focal)
            const float logit = pred_logits[(size_t)n * NC + cls[k]];
            const float p     = rcp(1.0f + ex2(-logit * LOG2E));
            const float omp   = 1.0f - p;
            const float pos   =  ALPHA         * omp * omp * (-(lg2(p   + 1e-8f) * LN2));
            const float neg   = (1.0f - ALPHA) * p   * p   * (-(lg2(omp + 1e-8f) * LN2));

            // GIoU
            const float area_t = (tb.z - tb.x) * (tb.w - tb.y);
            const float iw  = fmaxf(fminf(pb.z, tb.z) - fmaxf(pb.x, tb.x), 0.0f);
            const float ih  = fmaxf(fminf(pb.w, tb.w) - fmaxf(pb.y, tb.y), 0.0f);
            const float inter = iw * ih;
            const float uni   = area_p + area_t - inter;
            const float ew  = fmaxf(fmaxf(pb.z, tb.z) - fminf(pb.x, tb.x), 0.0f);
            const float eh  = fmaxf(fmaxf(pb.w, tb.w) - fminf(pb.y, tb.y), 0.0f);
            const float enc = ew * eh;
            const float giou = inter * rcp(uni) - (enc - uni) * rcp(enc);

            res[k] = W_BBOX * cb + W_CLASS * (pos - neg) - W_GIOU * giou;
        }
        *(float4*)(out + (size_t)n * T + j0) = make_float4(res[0], res[1], res[2], res[3]);
    } else {
        const int u    = t - NCT;
        const int n    = u >> 1;             // 2 groups of 4 per query
        const int half = u & 1;
        const int b    = n / Q;
        const int r0   = b * NI + half * 4;

        const float4 pb = *(const float4*)(pred_boxes + (size_t)n * 4);
        const float ra  = rcp((pb.z - pb.x) * (pb.w - pb.y));

        float res[4];
        #pragma unroll
        for (int k = 0; k < 4; ++k) {
            const float4 ib = *(const float4*)(ign_bbox + (size_t)(r0 + k) * 4);
            const float iw  = fmaxf(fminf(pb.z, ib.z) - fmaxf(pb.x, ib.x), 0.0f);
            const float ih  = fmaxf(fminf(pb.w, ib.w) - fmaxf(pb.y, ib.y), 0.0f);
            res[k] = iw * ih * ra;
        }
        *(float4*)(out + (size_t)CTOT + (size_t)n * NI + half * 4) =
            make_float4(res[0], res[1], res[2], res[3]);
    }
}

extern "C" void kernel_launch(void* const* d_in, const int* in_sizes, int n_in,
                              void* d_out, int out_size, void* d_ws, size_t ws_size,
                              hipStream_t stream) {
    const float* pred_logits = (const float*)d_in[0];
    const float* pred_boxes  = (const float*)d_in[1];
    const float* tgt_bbox    = (const float*)d_in[2];
    const float* ign_bbox    = (const float*)d_in[3];
    const float* img_sz      = (const float*)d_in[4];
    const float* img_sz_tgt  = (const float*)d_in[5];
    const int*   tgt_ids     = (const int*)d_in[6];
    float* out = (float*)d_out;

    const int blocks = (NTHREADS + 255) / 256;   // 1688
    matcher_kernel<<<blocks, 256, 0, stream>>>(
        pred_logits, pred_boxes, tgt_bbox, ign_bbox, img_sz, img_sz_tgt, tgt_ids, out);
}